// Round 17
// baseline (116.538 us; speedup 1.0000x reference)
//
#include <hip/hip_runtime.h>
#include <stdint.h>

// Problem constants
constexpr int C_IN  = 512;
constexpr int HW    = 784;            // 28*28
constexpr int NB    = 32;
constexpr int M_TOT = NB * HW;        // 25088 = 98*256
constexpr int N_TOT = 2000;
constexpr int NPAD  = 2048;           // = 8*256
constexpr int IMG_STRIDE = C_IN * HW;
constexpr int OUT_BATCH  = N_TOT * HW;

constexpr int PREPA_BLOCKS = M_TOT / 64;   // 392
constexpr int PREPW_BLOCKS = NPAD / 4;     // 512

typedef __attribute__((ext_vector_type(8))) short bf16x8;
typedef __attribute__((ext_vector_type(4))) float f32x4;

__device__ __forceinline__ uint16_t f2bf(float f) {
    union { float f; uint32_t u; } x; x.f = f;
    return (uint16_t)((x.u + 0x8000u) >> 16);
}

__device__ __forceinline__ void gload_lds16(const void* g, void* l) {
    __builtin_amdgcn_global_load_lds(
        (const __attribute__((address_space(1))) void*)g,
        (__attribute__((address_space(3))) void*)l, 16, 0, 0);
}

__device__ __forceinline__ f32x4 nt_load4(const float* p) {
    return __builtin_nontemporal_load((const f32x4*)p);
}

// ---------------------------------------------------------------------------
// prep: blocks [0,392): Abf[m][k] = bf16(input) transposed via LDS, fused s2[m]
//       blocks [392,904): Wbf[p][k] = bf16(w) (rows >= N_TOT zeroed), fused w2[p]
__global__ __launch_bounds__(256) void prep_kernel(const float* __restrict__ in,
                                                   const float* __restrict__ w,
                                                   short* __restrict__ Abf,
                                                   short* __restrict__ Wbf,
                                                   float* __restrict__ s2,
                                                   float* __restrict__ w2) {
    __shared__ __align__(16) char T[64 * 512 * 2];
    __shared__ float red[16][64];

    const int t = threadIdx.x;

    if (blockIdx.x >= PREPA_BLOCKS) {
        const int wv = t >> 6, lane = t & 63;
        const int p = (blockIdx.x - PREPA_BLOCKS) * 4 + wv;
        bf16x8 o = (bf16x8)0;
        float s = 0.f;
        if (p < N_TOT) {
            const float* base = w + (size_t)p * C_IN + lane * 8;
            f32x4 a = nt_load4(base);
            f32x4 c = nt_load4(base + 4);
            s = a[0]*a[0] + a[1]*a[1] + a[2]*a[2] + a[3]*a[3]
              + c[0]*c[0] + c[1]*c[1] + c[2]*c[2] + c[3]*c[3];
            o[0] = (short)f2bf(a[0]); o[1] = (short)f2bf(a[1]);
            o[2] = (short)f2bf(a[2]); o[3] = (short)f2bf(a[3]);
            o[4] = (short)f2bf(c[0]); o[5] = (short)f2bf(c[1]);
            o[6] = (short)f2bf(c[2]); o[7] = (short)f2bf(c[3]);
        }
        *(bf16x8*)(Wbf + (size_t)p * C_IN + lane * 8) = o;
#pragma unroll
        for (int off = 32; off; off >>= 1) s += __shfl_down(s, off);
        if (lane == 0) w2[p] = s;
        return;
    }

    const int q = t & 15;
    const int part = t >> 4;
    const int m0q = blockIdx.x * 64 + q * 4;
    const uint32_t b  = (uint32_t)m0q / 784u;
    const uint32_t hw = (uint32_t)m0q % 784u;
    const float* base = in + (size_t)b * IMG_STRIDE + hw;

    float acx = 0.f, acy = 0.f, acz = 0.f, acw = 0.f;
    const int c0 = part * 32;
#pragma unroll 4
    for (int c = c0; c < c0 + 32; ++c) {
        f32x4 v = nt_load4(base + (size_t)c * HW);
        acx = fmaf(v[0], v[0], acx);
        acy = fmaf(v[1], v[1], acy);
        acz = fmaf(v[2], v[2], acz);
        acw = fmaf(v[3], v[3], acw);
        uint16_t vals[4] = { f2bf(v[0]), f2bf(v[1]), f2bf(v[2]), f2bf(v[3]) };
        const uint32_t by0 = (uint32_t)(q * 4) * 1024u + (uint32_t)c * 2u;
#pragma unroll
        for (int j = 0; j < 4; ++j) {
            uint32_t bb = by0 + (uint32_t)j * 1024u;
            bb ^= ((bb >> 12) & 7u) << 4;
            *(uint16_t*)(T + bb) = vals[j];
        }
    }
    red[part][q * 4 + 0] = acx;
    red[part][q * 4 + 1] = acy;
    red[part][q * 4 + 2] = acz;
    red[part][q * 4 + 3] = acw;
    __syncthreads();
    if (t < 64) {
        float s = 0.f;
#pragma unroll
        for (int p = 0; p < 16; ++p) s += red[p][t];
        s2[blockIdx.x * 64 + t] = s;
    }
    short* dst = Abf + (size_t)blockIdx.x * 64 * 512;
#pragma unroll
    for (int i = 0; i < 16; ++i) {
        const int idx = i * 256 + t;
        const int row = idx >> 6, ch = idx & 63;
        uint32_t bb = (uint32_t)row * 1024u + (uint32_t)ch * 16u;
        bb ^= ((bb >> 12) & 7u) << 4;
        bf16x8 v = *(bf16x8*)(T + bb);
        *(bf16x8*)(dst + (size_t)row * 512 + ch * 8) = v;
    }
}

// ---------------------------------------------------------------------------
// gemm16: faithful 256x256 8-phase port. 8 waves (2M x 4N, wave 128x64),
// BK=64, 8 K-tiles. LDS 128 KB = 2 buffers x (A 32K + B 32K); each buffer's
// A is stored mh-strip-contiguous, B nh-strip-contiguous (strip = 16 KB =
// 2 gload_lds). Per phase (quadrant): {12 ds_read || 1 strip stage ->
// barrier -> lgkmcnt(0) -> setprio(1) 16 MFMA setprio(0) -> barrier}.
// Stage schedule: q0->A1(T+1), q1->B1(T+1), q2->A0(T+2), q3->B0(T+2);
// every target slot's last reader finished at the barrier before the issue.
// vmcnt(4) at tile boundaries only (0 at T=6). Verified 0-conflict slot
// swizzle: storage slot s of storage-row r holds logical k-group s^(r&7).
__global__ __launch_bounds__(512, 1) void gemm16_kernel(const short* __restrict__ Abf,
                                                        const short* __restrict__ Wbf,
                                                        const float* __restrict__ s2,
                                                        const float* __restrict__ w2,
                                                        float* __restrict__ out) {
    __shared__ __align__(16) char smem[131072];   // 2 x 64 KB

    const int t = threadIdx.x;
    const int wv = t >> 6, lane = t & 63;
    const int lr = lane & 15, lg = lane >> 4;

    // XCD window remap: 784 = 8*98 blocks; each XCD owns ~12 contiguous bm
    // x all 8 bn (A window ~3 MB + B 2 MB).
    const int bid = blockIdx.x;
    const int L  = (bid & 7) * 98 + (bid >> 3);
    const int bm = L >> 3;               // 0..97
    const int bn = L & 7;                // 0..7

    // ---- staging precompute (linear LDS dest, pre-swizzled global source)
    const int gA  = (t & 7) ^ ((t >> 3) & 7);      // logical k-group for my slot
    const int d16 = t * 16;                        // dest byte within 8 KB chunk
    const int nb0 = ((t >> 3) >> 5) * 64 + ((t >> 3) & 31);   // B row base, j=0
    const short* Asrc = Abf + (size_t)(bm * 256 + (t >> 3)) * 512 + gA * 8;
    const short* Bsrc = Wbf + (size_t)(bn * 256 + nb0) * 512 + gA * 8;

    // ---- wave -> 128m x 64n subtile
    const int wm = (wv >> 2) * 128;      // {0,128}
    const int wn = (wv & 3) * 64;        // {0,64,128,192}

    // ---- ds_read bases. A storage row = mh*128 + (wm>>7)*64 + frag*16 + lr
    //      B storage row = nh*128 + (wn>>6)*32 + frag*16 + lr  (B at +32768)
    //      slot = (kk*4+lg) ^ (lr&7);  kk=1 byte addr = kk=0 addr ^ 64
    const int aoff0 = (wm >> 7) * 8192 + lr * 128 + ((lg ^ (lr & 7)) * 16);
    const int boff0 = 32768 + (wn >> 6) * 4096 + lr * 128 + ((lg ^ (lr & 7)) * 16);

    f32x4 acc[8][4] = {};   // acc[mh*4+fm][nh*2+fn]

    // stage one A strip (mh) of tile TT: storage rows [mh*128, +128)
#define STAGE_A(TT, MH)                                                        \
    do {                                                                       \
        char* db_ = smem + ((TT) & 1) * 65536;                                 \
        const short* s_ = Asrc + (size_t)(MH) * 64 * 512 + (TT) * 64;          \
        gload_lds16(s_,             db_ + (MH) * 16384 + d16);                 \
        gload_lds16(s_ + 128 * 512, db_ + (MH) * 16384 + 8192 + d16);          \
    } while (0)
    // stage one B strip (nh): storage rows [nh*128, +128) of B region
#define STAGE_B(TT, NH)                                                        \
    do {                                                                       \
        char* db_ = smem + ((TT) & 1) * 65536;                                 \
        const short* s_ = Bsrc + (size_t)(NH) * 32 * 512 + (TT) * 64;          \
        gload_lds16(s_,             db_ + 32768 + (NH) * 16384 + d16);         \
        gload_lds16(s_ + 128 * 512, db_ + 32768 + (NH) * 16384 + 8192 + d16);  \
    } while (0)

#define PHASE(TT, MH, NH, STAGE_STMT, GATE_STMT)                               \
    do {                                                                       \
        const char* buf_ = smem + ((TT) & 1) * 65536;                          \
        bf16x8 af[4][2], bfr[2][2];                                            \
        _Pragma("unroll") for (int f = 0; f < 4; ++f) {                        \
            const int a0_ = (MH) * 16384 + f * 2048 + aoff0;                   \
            af[f][0] = *(const bf16x8*)(buf_ + a0_);                           \
            af[f][1] = *(const bf16x8*)(buf_ + (a0_ ^ 64));                    \
        }                                                                      \
        _Pragma("unroll") for (int f = 0; f < 2; ++f) {                        \
            const int b0_ = (NH) * 16384 + f * 2048 + boff0;                   \
            bfr[f][0] = *(const bf16x8*)(buf_ + b0_);                          \
            bfr[f][1] = *(const bf16x8*)(buf_ + (b0_ ^ 64));                   \
        }                                                                      \
        STAGE_STMT;                                                            \
        __builtin_amdgcn_sched_barrier(0);                                     \
        __builtin_amdgcn_s_barrier();                                          \
        asm volatile("s_waitcnt lgkmcnt(0)" ::: "memory");                     \
        __builtin_amdgcn_sched_barrier(0);                                     \
        __builtin_amdgcn_s_setprio(1);                                         \
        _Pragma("unroll") for (int fm = 0; fm < 4; ++fm)                       \
        _Pragma("unroll") for (int fn = 0; fn < 2; ++fn) {                     \
            acc[(MH)*4+fm][(NH)*2+fn] =                                        \
                __builtin_amdgcn_mfma_f32_16x16x32_bf16(                       \
                    af[fm][0], bfr[fn][0], acc[(MH)*4+fm][(NH)*2+fn], 0,0,0);  \
            acc[(MH)*4+fm][(NH)*2+fn] =                                        \
                __builtin_amdgcn_mfma_f32_16x16x32_bf16(                       \
                    af[fm][1], bfr[fn][1], acc[(MH)*4+fm][(NH)*2+fn], 0,0,0);  \
        }                                                                      \
        __builtin_amdgcn_s_setprio(0);                                         \
        GATE_STMT;                                                             \
        __builtin_amdgcn_sched_barrier(0);                                     \
        __builtin_amdgcn_s_barrier();                                          \
        __builtin_amdgcn_sched_barrier(0);                                     \
    } while (0)

    // prologue: tile 0 (4 strips) + A0(1), B0(1); gate: tile 0's 8 landed
    STAGE_A(0, 0); STAGE_A(0, 1); STAGE_B(0, 0); STAGE_B(0, 1);
    STAGE_A(1, 0); STAGE_B(1, 0);
    asm volatile("s_waitcnt vmcnt(4)" ::: "memory");
    __builtin_amdgcn_sched_barrier(0);
    __builtin_amdgcn_s_barrier();
    __builtin_amdgcn_sched_barrier(0);

#pragma unroll
    for (int T = 0; T < 8; ++T) {
        PHASE(T, 0, 0, if (T + 1 < 8) STAGE_A(T + 1, 1), );
        PHASE(T, 0, 1, if (T + 1 < 8) STAGE_B(T + 1, 1), );
        PHASE(T, 1, 0, if (T + 2 < 8) STAGE_A(T + 2, 0), );
        PHASE(T, 1, 1, if (T + 2 < 8) STAGE_B(T + 2, 0),
              if (T < 6)       { asm volatile("s_waitcnt vmcnt(4)" ::: "memory"); }
              else if (T == 6) { asm volatile("s_waitcnt vmcnt(0)" ::: "memory"); });
    }
#undef PHASE
#undef STAGE_A
#undef STAGE_B

    // epilogue: relu(s2 - 2*acc + w2); m = wm + (m'>>2)*64 + (m'&3)*16 + lg*4,
    // n = wn + (n'>>1)*32 + (n'&1)*16 + lr
    float wreg[4];
    int n_ok[4];
#pragma unroll
    for (int n = 0; n < 4; ++n) {
        const int n_o = bn * 256 + wn + (n >> 1) * 32 + (n & 1) * 16 + lr;
        n_ok[n] = (n_o < N_TOT);
        wreg[n] = n_ok[n] ? w2[n_o] : 0.f;
    }
#pragma unroll
    for (int m = 0; m < 8; ++m) {
        const int m_r = bm * 256 + wm + (m >> 2) * 64 + (m & 3) * 16 + lg * 4;
        const f32x4 s2v = *(const f32x4*)(s2 + m_r);
        const uint32_t ob  = (uint32_t)m_r / 784u;
        const uint32_t ohw = (uint32_t)m_r % 784u;
        float* obase = out + (size_t)ob * OUT_BATCH + ohw;
#pragma unroll
        for (int n = 0; n < 4; ++n) {
            if (n_ok[n]) {
                const int n_o = bn * 256 + wn + (n >> 1) * 32 + (n & 1) * 16 + lr;
                const f32x4 a = acc[m][n];
                f32x4 r;
                r[0] = fmaxf(s2v[0] - 2.f * a[0] + wreg[n], 0.f);
                r[1] = fmaxf(s2v[1] - 2.f * a[1] + wreg[n], 0.f);
                r[2] = fmaxf(s2v[2] - 2.f * a[2] + wreg[n], 0.f);
                r[3] = fmaxf(s2v[3] - 2.f * a[3] + wreg[n], 0.f);
                *(f32x4*)(obase + (size_t)n_o * HW) = r;
            }
        }
    }
}

// ---------------------------------------------------------------------------
extern "C" void kernel_launch(void* const* d_in, const int* in_sizes, int n_in,
                              void* d_out, int out_size, void* d_ws, size_t ws_size,
                              hipStream_t stream) {
    const float* in = (const float*)d_in[0];   // [32,512,28,28] fp32
    const float* w  = (const float*)d_in[1];   // [2000,512,1,1] fp32
    float* out = (float*)d_out;                // [32,2000,28,28] fp32

    const size_t offA  = 0;
    const size_t offW  = offA + (size_t)M_TOT * C_IN * sizeof(short);   // 25.7 MB
    const size_t offS2 = offW + (size_t)NPAD * C_IN * sizeof(short);    // +2.1 MB
    const size_t offW2 = offS2 + (size_t)M_TOT * sizeof(float);

    short* Abf = (short*)((char*)d_ws + offA);
    short* Wbf = (short*)((char*)d_ws + offW);
    float* s2  = (float*)((char*)d_ws + offS2);
    float* w2  = (float*)((char*)d_ws + offW2);

    prep_kernel<<<PREPA_BLOCKS + PREPW_BLOCKS, 256, 0, stream>>>(in, w, Abf, Wbf, s2, w2);

    // 98 m-tiles x 8 n-tiles = 784 blocks, 512 threads, 1 block/CU
    gemm16_kernel<<<98 * 8, 512, 0, stream>>>(Abf, Wbf, s2, w2, out);
}

// Round 18
// 94.809 us; speedup vs baseline: 1.2292x; 1.2292x over previous
//
#include <hip/hip_runtime.h>
#include <stdint.h>

// Problem constants
constexpr int C_IN  = 512;
constexpr int HW    = 784;            // 28*28
constexpr int NB    = 32;
constexpr int M_TOT = NB * HW;        // 25088 = 98*256
constexpr int N_TOT = 2000;
constexpr int NPAD  = 2048;
constexpr int IMG_STRIDE = C_IN * HW;
constexpr int OUT_BATCH  = N_TOT * HW;

// GEMM tiling: 256x128 block, 4 waves (wave 128x64), BK=32, ring-3, 2 blk/CU
constexpr int TBM = 256;
constexpr int TBN = 128;
constexpr int NKT = C_IN / 32;        // 16

constexpr int PREPA_BLOCKS = M_TOT / 64;   // 392
constexpr int PREPW_BLOCKS = NPAD / 4;     // 512

typedef __attribute__((ext_vector_type(8))) short bf16x8;
typedef __attribute__((ext_vector_type(4))) float f32x4;

__device__ __forceinline__ uint16_t f2bf(float f) {
    union { float f; uint32_t u; } x; x.f = f;
    return (uint16_t)((x.u + 0x8000u) >> 16);
}

__device__ __forceinline__ void gload_lds16(const void* g, void* l) {
    __builtin_amdgcn_global_load_lds(
        (const __attribute__((address_space(1))) void*)g,
        (__attribute__((address_space(3))) void*)l, 16, 0, 0);
}

// non-temporal 16B LOAD only (read-once input streams). nt STORES measured
// +100 MB WRITE inflation (round 13) — do not use.
__device__ __forceinline__ f32x4 nt_load4(const float* p) {
    return __builtin_nontemporal_load((const f32x4*)p);
}

// ---------------------------------------------------------------------------
// prep: blocks [0,392): Abf[m][k] = bf16(input) transposed via LDS, fused s2[m]
//       blocks [392,904): Wbf[p][k] = bf16(w) (rows >= N_TOT zeroed), fused w2[p]
__global__ __launch_bounds__(256) void prep_kernel(const float* __restrict__ in,
                                                   const float* __restrict__ w,
                                                   short* __restrict__ Abf,
                                                   short* __restrict__ Wbf,
                                                   float* __restrict__ s2,
                                                   float* __restrict__ w2) {
    __shared__ __align__(16) char T[64 * 512 * 2];
    __shared__ float red[16][64];

    const int t = threadIdx.x;

    if (blockIdx.x >= PREPA_BLOCKS) {
        const int wv = t >> 6, lane = t & 63;
        const int p = (blockIdx.x - PREPA_BLOCKS) * 4 + wv;
        bf16x8 o = (bf16x8)0;
        float s = 0.f;
        if (p < N_TOT) {
            const float* base = w + (size_t)p * C_IN + lane * 8;
            f32x4 a = nt_load4(base);
            f32x4 c = nt_load4(base + 4);
            s = a[0]*a[0] + a[1]*a[1] + a[2]*a[2] + a[3]*a[3]
              + c[0]*c[0] + c[1]*c[1] + c[2]*c[2] + c[3]*c[3];
            o[0] = (short)f2bf(a[0]); o[1] = (short)f2bf(a[1]);
            o[2] = (short)f2bf(a[2]); o[3] = (short)f2bf(a[3]);
            o[4] = (short)f2bf(c[0]); o[5] = (short)f2bf(c[1]);
            o[6] = (short)f2bf(c[2]); o[7] = (short)f2bf(c[3]);
        }
        *(bf16x8*)(Wbf + (size_t)p * C_IN + lane * 8) = o;
#pragma unroll
        for (int off = 32; off; off >>= 1) s += __shfl_down(s, off);
        if (lane == 0) w2[p] = s;
        return;
    }

    const int q = t & 15;
    const int part = t >> 4;
    const int m0q = blockIdx.x * 64 + q * 4;
    const uint32_t b  = (uint32_t)m0q / 784u;
    const uint32_t hw = (uint32_t)m0q % 784u;
    const float* base = in + (size_t)b * IMG_STRIDE + hw;

    float acx = 0.f, acy = 0.f, acz = 0.f, acw = 0.f;
    const int c0 = part * 32;
#pragma unroll 4
    for (int c = c0; c < c0 + 32; ++c) {
        f32x4 v = nt_load4(base + (size_t)c * HW);
        acx = fmaf(v[0], v[0], acx);
        acy = fmaf(v[1], v[1], acy);
        acz = fmaf(v[2], v[2], acz);
        acw = fmaf(v[3], v[3], acw);
        uint16_t vals[4] = { f2bf(v[0]), f2bf(v[1]), f2bf(v[2]), f2bf(v[3]) };
        const uint32_t by0 = (uint32_t)(q * 4) * 1024u + (uint32_t)c * 2u;
#pragma unroll
        for (int j = 0; j < 4; ++j) {
            uint32_t bb = by0 + (uint32_t)j * 1024u;
            bb ^= ((bb >> 12) & 7u) << 4;
            *(uint16_t*)(T + bb) = vals[j];
        }
    }
    red[part][q * 4 + 0] = acx;
    red[part][q * 4 + 1] = acy;
    red[part][q * 4 + 2] = acz;
    red[part][q * 4 + 3] = acw;
    __syncthreads();
    if (t < 64) {
        float s = 0.f;
#pragma unroll
        for (int p = 0; p < 16; ++p) s += red[p][t];
        s2[blockIdx.x * 64 + t] = s;
    }
    short* dst = Abf + (size_t)blockIdx.x * 64 * 512;
#pragma unroll
    for (int i = 0; i < 16; ++i) {
        const int idx = i * 256 + t;
        const int row = idx >> 6, ch = idx & 63;
        uint32_t bb = (uint32_t)row * 1024u + (uint32_t)ch * 16u;
        bb ^= ((bb >> 12) & 7u) << 4;
        bf16x8 v = *(bf16x8*)(T + bb);
        *(bf16x8*)(dst + (size_t)row * 512 + ch * 8) = v;
    }
}

// ---------------------------------------------------------------------------
// gemm13 (round-14 winner, 94.8 us total): 256x128 block, 4 waves of 128x64,
// BK=32, ring-3 LDS (72 KB -> 2 blocks/CU), single barrier + counted vmcnt(6)
// per K-tile (never drains mid-loop), measured-0-conflict slot swizzle
// (linear LDS dest + pre-swizzled global source), setprio around MFMA,
// XCD-locality remap (each XCD's resident window ~3 MB < 4 MB L2).
__global__ __launch_bounds__(256, 2) void gemm13_kernel(const short* __restrict__ Abf,
                                                        const short* __restrict__ Wbf,
                                                        const float* __restrict__ s2,
                                                        const float* __restrict__ w2,
                                                        float* __restrict__ out) {
    __shared__ __align__(16) char smem[3 * 24576];   // 72 KB

    const int t = threadIdx.x;
    const int wv = t >> 6, lane = t & 63;
    const int lr = lane & 15, lg = lane >> 4;

    // XCD-locality mapping (bijective for 1568 = 8*196 blocks)
    const int bid = blockIdx.x;
    const int L  = (bid & 7) * 196 + (bid >> 3);
    const int bm = L >> 4;               // 0..97
    const int bn = L & 15;               // 0..15

    const short* Ap = Abf + (size_t)bm * TBM * C_IN;
    const short* Bp = Wbf + (size_t)bn * TBN * C_IN;

    // staging: instr j dest = buf + jbase + t*16 -> row = jrow + wv*16 +
    // (lane>>2), storage slot = lane&3; source logical k-group =
    // (lane&3) ^ ((row>>1)&3) = (lane&3)^((lane>>3)&3)
    const int srow = wv * 16 + (lane >> 2);
    const int sg   = (lane & 3) ^ ((lane >> 3) & 3);
    const short* AsrcL = Ap + (size_t)srow * C_IN + sg * 8;   // + j*64 rows
    const short* BsrcL = Bp + (size_t)srow * C_IN + sg * 8;   // + j*64 rows
    const int dst = t * 16;

    // wave -> output subtile (128m x 64n)
    const int wm = (wv >> 1) * 128;        // {0,128}
    const int wn = (wv & 1) * 64;          // {0,64}

    // ds_read: row r at 64 B stride, slot lg^((lr>>1)&3)
    const int slot  = lg ^ ((lr >> 1) & 3);
    const int abase = (wm + lr) * 64 + slot * 16;            // + m*1024
    const int bbase = 16384 + (wn + lr) * 64 + slot * 16;    // + n*1024

    f32x4 acc[8][4] = {};

#define STAGE(tt)                                                              \
    do {                                                                       \
        char* buf_ = smem + ((tt) % 3) * 24576;                                \
        const short* as_ = AsrcL + (tt) * 32;                                  \
        const short* bs_ = BsrcL + (tt) * 32;                                  \
        gload_lds16(as_,              buf_ + dst);                             \
        gload_lds16(as_ +  64 * C_IN, buf_ + 4096 + dst);                      \
        gload_lds16(as_ + 128 * C_IN, buf_ + 8192 + dst);                      \
        gload_lds16(as_ + 192 * C_IN, buf_ + 12288 + dst);                     \
        gload_lds16(bs_,              buf_ + 16384 + dst);                     \
        gload_lds16(bs_ +  64 * C_IN, buf_ + 20480 + dst);                     \
    } while (0)

    // prologue: issue stages for tiles 0,1 (12 loads in flight)
    STAGE(0);
    STAGE(1);

#pragma unroll
    for (int kt = 0; kt < NKT; ++kt) {
        // entry gate: my stage(kt) landed; stage(kt+1)'s 6 stay in flight
        if (kt < NKT - 1) asm volatile("s_waitcnt vmcnt(6)" ::: "memory");
        else              asm volatile("s_waitcnt vmcnt(0)" ::: "memory");
        __builtin_amdgcn_sched_barrier(0);
        __builtin_amdgcn_s_barrier();      // all waves' stage(kt) landed;
        __builtin_amdgcn_sched_barrier(0); // buf (kt+2)%3 fully consumed (iter kt-1)

        if (kt + 2 < NKT) STAGE(kt + 2);   // into buffer freed at this barrier

        const char* buf = smem + (kt % 3) * 24576;
        bf16x8 bfrag[4], afrag[8];
#pragma unroll
        for (int n = 0; n < 4; ++n)
            bfrag[n] = *(const bf16x8*)(buf + bbase + n * 1024);
#pragma unroll
        for (int m = 0; m < 8; ++m)
            afrag[m] = *(const bf16x8*)(buf + abase + m * 1024);

        __builtin_amdgcn_s_setprio(1);
#pragma unroll
        for (int m = 0; m < 8; ++m)
#pragma unroll
            for (int n = 0; n < 4; ++n)
                acc[m][n] = __builtin_amdgcn_mfma_f32_16x16x32_bf16(
                    afrag[m], bfrag[n], acc[m][n], 0, 0, 0);
        __builtin_amdgcn_s_setprio(0);
    }
#undef STAGE

    // epilogue: relu(s2 - 2*acc + w2), regular f32x4 stores
    float wreg[4];
    int n_ok[4];
#pragma unroll
    for (int n = 0; n < 4; ++n) {
        const int n_o = bn * TBN + wn + n * 16 + lr;
        n_ok[n] = (n_o < N_TOT);
        wreg[n] = n_ok[n] ? w2[n_o] : 0.f;
    }
#pragma unroll
    for (int m = 0; m < 8; ++m) {
        const int m_r = bm * TBM + wm + m * 16 + lg * 4;   // 4-aligned, 784%4==0
        const f32x4 s2v = *(const f32x4*)(s2 + m_r);
        const uint32_t ob  = (uint32_t)m_r / 784u;
        const uint32_t ohw = (uint32_t)m_r % 784u;
        float* obase = out + (size_t)ob * OUT_BATCH + ohw;
#pragma unroll
        for (int n = 0; n < 4; ++n) {
            if (n_ok[n]) {
                const int n_o = bn * TBN + wn + n * 16 + lr;
                const f32x4 a = acc[m][n];
                f32x4 r;
                r[0] = fmaxf(s2v[0] - 2.f * a[0] + wreg[n], 0.f);
                r[1] = fmaxf(s2v[1] - 2.f * a[1] + wreg[n], 0.f);
                r[2] = fmaxf(s2v[2] - 2.f * a[2] + wreg[n], 0.f);
                r[3] = fmaxf(s2v[3] - 2.f * a[3] + wreg[n], 0.f);
                *(f32x4*)(obase + (size_t)n_o * HW) = r;
            }
        }
    }
}

// ---------------------------------------------------------------------------
extern "C" void kernel_launch(void* const* d_in, const int* in_sizes, int n_in,
                              void* d_out, int out_size, void* d_ws, size_t ws_size,
                              hipStream_t stream) {
    const float* in = (const float*)d_in[0];   // [32,512,28,28] fp32
    const float* w  = (const float*)d_in[1];   // [2000,512,1,1] fp32
    float* out = (float*)d_out;                // [32,2000,28,28] fp32

    const size_t offA  = 0;
    const size_t offW  = offA + (size_t)M_TOT * C_IN * sizeof(short);   // 25.7 MB
    const size_t offS2 = offW + (size_t)NPAD * C_IN * sizeof(short);    // +2.1 MB
    const size_t offW2 = offS2 + (size_t)M_TOT * sizeof(float);

    short* Abf = (short*)((char*)d_ws + offA);
    short* Wbf = (short*)((char*)d_ws + offW);
    float* s2  = (float*)((char*)d_ws + offS2);
    float* w2  = (float*)((char*)d_ws + offW2);

    prep_kernel<<<PREPA_BLOCKS + PREPW_BLOCKS, 256, 0, stream>>>(in, w, Abf, Wbf, s2, w2);

    // 98 m-tiles x 16 n-tiles = 1568 blocks, 2 resident per CU (3.06 rounds)
    gemm13_kernel<<<98 * 16, 256, 0, stream>>>(Abf, Wbf, s2, w2, out);
}